// Round 7
// baseline (350.971 us; speedup 1.0000x reference)
//
#include <hip/hip_runtime.h>

#define NODE_DIM 128
#define NUM_IRREPS 224
#define SPH_DIM 480
#define HIDDEN 576   // NODE_DIM + 2*NUM_IRREPS
#define NUM_BASIS 20
#define N_NODES 10000
#define N_EDGES 160000
#define NPB 8        // nodes per block in node MLP

// ---------------- init: zero CSR counts ----------------
__global__ void init_counts(int* __restrict__ counts) {
    int i = blockIdx.x * blockDim.x + threadIdx.x;
    if (i < N_NODES) counts[i] = 0;
}

// ---------------- node MLP: scalar_out = silu(x@W1+b1)@W2+b2 ----------------
__global__ __launch_bounds__(128) void node_mlp(
    const float* __restrict__ x,
    const float* __restrict__ W1, const float* __restrict__ b1,
    const float* __restrict__ W2, const float* __restrict__ b2,
    float* __restrict__ so) {
    __shared__ float xs[NPB][NODE_DIM];
    __shared__ float hs[NPB][NODE_DIM];
    const int tid = threadIdx.x;
    const int n0 = blockIdx.x * NPB;

    #pragma unroll
    for (int n = 0; n < NPB; ++n) {
        int node = n0 + n;
        xs[n][tid] = (node < N_NODES) ? x[(size_t)node * NODE_DIM + tid] : 0.f;
    }
    __syncthreads();

    float acc[NPB];
    #pragma unroll
    for (int n = 0; n < NPB; ++n) acc[n] = b1[tid];
    for (int k = 0; k < NODE_DIM; ++k) {
        float w = W1[k * NODE_DIM + tid];
        #pragma unroll
        for (int n = 0; n < NPB; ++n) acc[n] = fmaf(xs[n][k], w, acc[n]);
    }
    #pragma unroll
    for (int n = 0; n < NPB; ++n) {
        float v = acc[n];
        hs[n][tid] = v / (1.f + __expf(-v));
    }
    __syncthreads();

    for (int j = tid; j < HIDDEN; j += 128) {
        float a2[NPB];
        #pragma unroll
        for (int n = 0; n < NPB; ++n) a2[n] = b2[j];
        for (int k = 0; k < NODE_DIM; ++k) {
            float w = W2[k * HIDDEN + j];
            #pragma unroll
            for (int n = 0; n < NPB; ++n) a2[n] = fmaf(hs[n][k], w, a2[n]);
        }
        #pragma unroll
        for (int n = 0; n < NPB; ++n) {
            int node = n0 + n;
            if (node < N_NODES) so[(size_t)node * HIDDEN + j] = a2[n];
        }
    }
}

// ---------------- CSR build: histogram / scan / scatter ----------------
__global__ __launch_bounds__(256) void hist_kernel(const int* __restrict__ eidx,
                                                   int* __restrict__ counts) {
    int i = blockIdx.x * blockDim.x + threadIdx.x;
    if (i < N_EDGES) atomicAdd(&counts[eidx[i]], 1);   // bucket by src
}

__global__ __launch_bounds__(1024) void scan_kernel(const int* __restrict__ counts,
                                                    int* __restrict__ offsets,
                                                    int* __restrict__ cursor) {
    __shared__ int wsum[16];
    const int tid = threadIdx.x;
    int vals[10];
    int run = 0;
    #pragma unroll
    for (int i = 0; i < 10; ++i) {
        int idx = tid * 10 + i;
        int c = (idx < N_NODES) ? counts[idx] : 0;
        vals[i] = run;
        run += c;
    }
    const int lane = tid & 63, w = tid >> 6;
    int inc = run;
    #pragma unroll
    for (int off = 1; off < 64; off <<= 1) {
        int v = __shfl_up(inc, off);
        if (lane >= off) inc += v;
    }
    if (lane == 63) wsum[w] = inc;
    __syncthreads();
    if (w == 0) {
        int v = (lane < 16) ? wsum[lane] : 0;
        #pragma unroll
        for (int off = 1; off < 16; off <<= 1) {
            int u = __shfl_up(v, off);
            if (lane >= off) v += u;
        }
        if (lane < 16) wsum[lane] = v;
    }
    __syncthreads();
    const int wbase = (w > 0) ? wsum[w - 1] : 0;
    const int base = wbase + inc - run;   // exclusive prefix
    #pragma unroll
    for (int i = 0; i < 10; ++i) {
        int idx = tid * 10 + i;
        if (idx < N_NODES) {
            int v = base + vals[i];
            offsets[idx] = v;
            cursor[idx] = v;
        }
    }
    if (tid == 1023) offsets[N_NODES] = wbase + inc;
}

__global__ __launch_bounds__(256) void scatter_kernel(const int* __restrict__ eidx,
                                                      int* __restrict__ cursor,
                                                      int* __restrict__ edge_order) {
    int i = blockIdx.x * blockDim.x + threadIdx.x;
    if (i < N_EDGES) {
        int s = eidx[i];
        int pos = atomicAdd(&cursor[s], 1);
        edge_order[pos] = i;
    }
}

// ---------------- node gather v3: coalesced sph, LDS fo-exchange ----------------
// Phase-1 (per edge): thread t<224 computes fo pair for irrep t (cols t, 224+t);
//   t<128 additionally accumulates scalar col 448+t. Pairs go to LDS.
// Phase-2: thread t consumes sph elements d=t (all) and d=256+t (t<224) —
//   fully coalesced xsp/rsh loads; fo via ds_read_b64 (broadcast-friendly).
// Software pipeline: payload(e+2) issued at top; raw lgkmcnt+barrier keeps
// global loads in flight across the barrier (no vmcnt drain).
#define DOTN(a, W) do { \
    a = fmaf(qn0.x, W[0], a);  a = fmaf(qn0.y, W[1], a);  a = fmaf(qn0.z, W[2], a);  a = fmaf(qn0.w, W[3], a); \
    a = fmaf(qn1.x, W[4], a);  a = fmaf(qn1.y, W[5], a);  a = fmaf(qn1.z, W[6], a);  a = fmaf(qn1.w, W[7], a); \
    a = fmaf(qn2.x, W[8], a);  a = fmaf(qn2.y, W[9], a);  a = fmaf(qn2.z, W[10], a); a = fmaf(qn2.w, W[11], a); \
    a = fmaf(qn3.x, W[12], a); a = fmaf(qn3.y, W[13], a); a = fmaf(qn3.z, W[14], a); a = fmaf(qn3.w, W[15], a); \
    a = fmaf(qn4.x, W[16], a); a = fmaf(qn4.y, W[17], a); a = fmaf(qn4.z, W[18], a); a = fmaf(qn4.w, W[19], a); \
} while (0)

#define LOADN(E, D, F) do { \
    const float4* rq_ = (const float4*)(rbf + (size_t)(E) * NUM_BASIS); \
    qn0 = rq_[0]; qn1 = rq_[1]; qn2 = rq_[2]; qn3 = rq_[3]; qn4 = rq_[4]; \
    const float* sod_ = so + (size_t)(D) * HIDDEN; \
    s0n = sod_[c0]; s1n = sod_[c1]; s2n = hasSc ? sod_[c2] : 0.f; \
    const float* x_ = xsp + (size_t)(D) * SPH_DIM; \
    const float* r_ = rsh + (size_t)(E) * SPH_DIM; \
    x1n = x_[t]; r1n = r_[t]; \
    if (t < 224) { x2n = x_[256 + t]; r2n = r_[256 + t]; } \
    fn = (F); \
} while (0)

#define LOADW(E, D, F) do { \
    const float4* rq_ = (const float4*)(rbf + (size_t)(E) * NUM_BASIS); \
    qw0 = rq_[0]; qw1 = rq_[1]; qw2 = rq_[2]; qw3 = rq_[3]; qw4 = rq_[4]; \
    const float* sod_ = so + (size_t)(D) * HIDDEN; \
    s0w = sod_[c0]; s1w = sod_[c1]; s2w = hasSc ? sod_[c2] : 0.f; \
    const float* x_ = xsp + (size_t)(D) * SPH_DIM; \
    const float* r_ = rsh + (size_t)(E) * SPH_DIM; \
    x1w = x_[t]; r1w = r_[t]; \
    if (t < 224) { x2w = x_[256 + t]; r2w = r_[256 + t]; } \
    fw = (F); \
} while (0)

#define LGKM_BARRIER() do { \
    asm volatile("s_waitcnt lgkmcnt(0)" ::: "memory"); \
    __builtin_amdgcn_s_barrier(); \
} while (0)

__global__ __launch_bounds__(256) void node_gather(
    const float* __restrict__ xscal,
    const float* __restrict__ xsp,
    const float* __restrict__ rbf, const float* __restrict__ fcut,
    const float* __restrict__ rsh, const int* __restrict__ eidx,
    const float* __restrict__ Wr, const float* __restrict__ br,
    const float* __restrict__ so,
    const int* __restrict__ offsets, const int* __restrict__ edge_order,
    float* __restrict__ out_scalar, float* __restrict__ out_sph)
{
    __shared__ float2 fo_s[2][NUM_IRREPS];   // {gate_state, gate_edge} per irrep
    const int t = threadIdx.x;
    const int n = blockIdx.x;
    const bool hasIr = (t < 224);
    const bool hasSc = (t < 128);
    const int c0 = t;                    // gate_state col (hasIr)
    const int c1 = NUM_IRREPS + t;       // gate_edge col (hasIr)
    const int c2 = 2 * NUM_IRREPS + t;   // scalar col (hasSc)

    // gate indices for owned sph elements d1=t, d2=256+t
    const int g1i = (t < 128) ? t : (128 + (t - 128) / 3);
    const int g2i = (t < 64) ? (128 + (128 + t) / 3) : (192 + (t - 64) / 5);

    float w0[NUM_BASIS], w1[NUM_BASIS], w2[NUM_BASIS];
    #pragma unroll
    for (int k = 0; k < NUM_BASIS; ++k) {
        w0[k] = hasIr ? Wr[k * HIDDEN + c0] : 0.f;
        w1[k] = hasIr ? Wr[k * HIDDEN + c1] : 0.f;
        w2[k] = hasSc ? Wr[k * HIDDEN + c2] : 0.f;
    }
    const float bc0 = hasIr ? br[c0] : 0.f;
    const float bc1 = hasIr ? br[c1] : 0.f;
    const float bc2 = hasSc ? br[c2] : 0.f;

    const int beg  = offsets[n];
    const int end_ = offsets[n + 1];

    float accS = 0.f, accD1 = 0.f, accD2 = 0.f;

    if (beg < end_) {
        const int last = end_ - 1;
        int p = 0;

        float4 qn0, qn1, qn2, qn3, qn4, qw0, qw1, qw2, qw3, qw4;
        float s0n, s1n, s2n, s0w, s1w, s2w;
        float x1n, x2n = 0.f, r1n, r2n = 0.f;
        float x1w, x2w = 0.f, r1w, r2w = 0.f;
        float x1c, x2c = 0.f, r1c, r2c = 0.f;
        float fn, fw;

        // ---- prologue: edge 0 ----
        {
            int eA = edge_order[beg];
            int dA = eidx[N_EDGES + eA];
            float fA = fcut[eA];
            LOADN(eA, dA, fA);
        }
        {
            float a0 = bc0, a1 = bc1, a2 = bc2;
            DOTN(a0, w0); DOTN(a1, w1);
            if (hasSc) DOTN(a2, w2);
            if (hasIr) fo_s[0][t] = make_float2(a0 * fn * s0n, a1 * fn * s1n);
            if (hasSc) accS = fmaf(a2 * fn, s2n, accS);
        }
        x1c = x1n; r1c = r1n; x2c = x2n; r2c = r2n;
        // payload(1)
        {
            int eB = edge_order[min(beg + 1, last)];
            int dB = eidx[N_EDGES + eB];
            float fB = fcut[eB];
            LOADN(eB, dB, fB);
        }
        // meta for edge 2 and id for edge 3
        int e2m = edge_order[min(beg + 2, last)];
        int d2m = eidx[N_EDGES + e2m];
        float f2m = fcut[e2m];
        int e3m = edge_order[min(beg + 3, last)];

        LGKM_BARRIER();   // fo(0) visible

        for (int idx = beg; idx < end_; ++idx) {
            // 1. issue payload(idx+2)
            LOADW(e2m, d2m, f2m);
            // 2. compute fo(idx+1) from _n -> buf[p^1]; scalar accumulate
            {
                float a0 = bc0, a1 = bc1, a2 = bc2;
                DOTN(a0, w0); DOTN(a1, w1);
                if (hasSc) DOTN(a2, w2);
                if (hasIr) fo_s[p ^ 1][t] = make_float2(a0 * fn * s0n, a1 * fn * s1n);
                if (hasSc && (idx + 1 < end_)) accS = fmaf(a2 * fn, s2n, accS);
            }
            // 3. consume sph edge idx (coalesced x/r already in regs)
            {
                float2 fa = fo_s[p][g1i];
                accD1 = fmaf(x1c, fa.x, fmaf(r1c, fa.y, accD1));
                if (t < 224) {
                    float2 fb = fo_s[p][g2i];
                    accD2 = fmaf(x2c, fb.x, fmaf(r2c, fb.y, accD2));
                }
            }
            // 4. barrier (LDS only — global loads stay in flight)
            LGKM_BARRIER();
            // 5. rotate
            x1c = x1n; r1c = r1n; x2c = x2n; r2c = r2n;
            qn0 = qw0; qn1 = qw1; qn2 = qw2; qn3 = qw3; qn4 = qw4;
            s0n = s0w; s1n = s1w; s2n = s2w; fn = fw;
            x1n = x1w; r1n = r1w; x2n = x2w; r2n = r2w;
            e2m = e3m;
            d2m = eidx[N_EDGES + e3m];
            f2m = fcut[e3m];
            e3m = edge_order[min(idx + 4, last)];
            p ^= 1;
        }
    }

    // epilogue: out = x + acc (covers all outputs; init kernel not needed)
    if (t < 128) out_scalar[(size_t)n * NODE_DIM + t] = xscal[(size_t)n * NODE_DIM + t] + accS;
    out_sph[(size_t)n * SPH_DIM + t] = xsp[(size_t)n * SPH_DIM + t] + accD1;
    if (t < 224) out_sph[(size_t)n * SPH_DIM + 256 + t] = xsp[(size_t)n * SPH_DIM + 256 + t] + accD2;
}

extern "C" void kernel_launch(void* const* d_in, const int* in_sizes, int n_in,
                              void* d_out, int out_size, void* d_ws, size_t ws_size,
                              hipStream_t stream) {
    const float* x_scalar    = (const float*)d_in[0];
    const float* x_spherical = (const float*)d_in[1];
    const float* rbf         = (const float*)d_in[2];
    const float* fcut        = (const float*)d_in[3];
    const float* rsh         = (const float*)d_in[4];
    const int*   eidx        = (const int*)d_in[5];
    const float* W1          = (const float*)d_in[6];
    const float* b1          = (const float*)d_in[7];
    const float* W2          = (const float*)d_in[8];
    const float* b2          = (const float*)d_in[9];
    const float* Wr          = (const float*)d_in[10];
    const float* br          = (const float*)d_in[11];

    float* out        = (float*)d_out;
    float* out_scalar = out;                                   // (N_NODES, 128)
    float* out_sph    = out + (size_t)N_NODES * NODE_DIM;      // (N_NODES, 480)

    // workspace layout
    float* scalar_out = (float*)d_ws;                          // 10000*576 floats
    int*   counts     = (int*)(scalar_out + (size_t)N_NODES * HIDDEN);   // 10000
    int*   offsets    = counts + N_NODES;                      // 10001
    int*   cursor     = offsets + N_NODES + 1;                 // 10000
    int*   edge_order = cursor + N_NODES;                      // 160000

    init_counts<<<(N_NODES + 255) / 256, 256, 0, stream>>>(counts);
    hist_kernel<<<(N_EDGES + 255) / 256, 256, 0, stream>>>(eidx, counts);
    scan_kernel<<<1, 1024, 0, stream>>>(counts, offsets, cursor);
    scatter_kernel<<<(N_EDGES + 255) / 256, 256, 0, stream>>>(eidx, cursor, edge_order);
    node_mlp<<<(N_NODES + NPB - 1) / NPB, 128, 0, stream>>>(x_scalar, W1, b1, W2, b2, scalar_out);
    node_gather<<<N_NODES, 256, 0, stream>>>(x_scalar, x_spherical, rbf, fcut, rsh, eidx,
                                             Wr, br, scalar_out, offsets, edge_order,
                                             out_scalar, out_sph);
}